// Round 4
// baseline (194.048 us; speedup 1.0000x reference)
//
#include <hip/hip_runtime.h>

#define D_DIM 1024
#define B_DIM 128
#define C_DIM 1000
#define M_ALL 1152   // 128 x-rows + 1000 mu-rows + 24 zero-pad rows
#define EPSF 1e-6f
#define NBLK 256

typedef __attribute__((ext_vector_type(8))) short short8;   // 8 bf16 = 16B
typedef __attribute__((ext_vector_type(4))) float f32x4;

static __device__ __forceinline__ unsigned short f2bf(float f) {
    union { float f; unsigned int u; } v; v.f = f;
    unsigned int u = v.u;
    u += 0x7fffu + ((u >> 16) & 1u);   // round-to-nearest-even
    return (unsigned short)(u >> 16);
}

// Monotone-counter grid barrier: each block arrives once; spin until all did.
// Grid (256 blocks x 256 thr, <=16KB LDS, ~80 VGPR) is fully resident -> safe.
static __device__ __forceinline__ void grid_barrier(int* bar, int target) {
    __syncthreads();
    if (threadIdx.x == 0) {
        __threadfence();   // make this block's writes device-visible
        __hip_atomic_fetch_add(bar, 1, __ATOMIC_ACQ_REL, __HIP_MEMORY_SCOPE_AGENT);
        while (__hip_atomic_load(bar, __ATOMIC_ACQUIRE, __HIP_MEMORY_SCOPE_AGENT) < target)
            __builtin_amdgcn_s_sleep(8);
        __threadfence();   // acquire other blocks' writes
    }
    __syncthreads();
}

// Fragment layout: panel(tile16, kc) = 1KB: lane l = (k&31)>>3 * 16 + (row&15),
// j = k&7. offset_shorts = (tile*32 + kc)*512 + l*8 + j. One coalesced
// dwordx4 load per wave per panel = exactly one MFMA A/B operand.
__global__ __launch_bounds__(256)
void fused(const float* __restrict__ x, const float* __restrict__ mu,
           const float* __restrict__ beta, const float* __restrict__ L,
           const float* __restrict__ lmbda_p, const float* __restrict__ scale_p,
           unsigned short* __restrict__ A_frag, unsigned short* __restrict__ LT_frag,
           unsigned short* __restrict__ P_frag,
           float* __restrict__ nrm, float* __restrict__ bdot,
           int* __restrict__ bar, float* __restrict__ out) {
    __shared__ __align__(16) unsigned short s_tile[64 * 72];  // 9216B, reused
    __shared__ float red[2][4];
    const int tid = threadIdx.x, bid = blockIdx.x;
    const int lane = tid & 63, wv = tid >> 6;
    const int lrow = lane & 15, q = lane >> 4;
    const int gid = bid * 4 + wv;            // 0..1023

    // ================= Phase 1a: pack A rows + per-row reductions ==========
    for (int it = 0; it < 5; ++it) {
        int m = it * NBLK + bid;
        if (m < M_ALL) {
            float4 v;
            if (m < B_DIM)              v = *(const float4*)(x + m * D_DIM + tid * 4);
            else if (m < B_DIM + C_DIM) v = *(const float4*)(mu + (m - B_DIM) * D_DIM + tid * 4);
            else                        v = make_float4(0.f, 0.f, 0.f, 0.f);
            ushort4 o;
            o.x = f2bf(v.x); o.y = f2bf(v.y); o.z = f2bf(v.z); o.w = f2bf(v.w);
            // k = tid*4: kc = tid>>3, qk = (tid>>1)&3, j = (tid&1)*4
            int mtile = m >> 4, kc = tid >> 3, qk = (tid >> 1) & 3, jj = (tid & 1) * 4;
            int lfr = qk * 16 + (m & 15);
            *(ushort4*)(A_frag + (mtile * 32 + kc) * 512 + lfr * 8 + jj) = o;

            float4 bt4 = *(const float4*)(beta + tid * 4);
            float sa = v.x*v.x + v.y*v.y + v.z*v.z + v.w*v.w;
            float sb = bt4.x*v.x + bt4.y*v.y + bt4.z*v.z + bt4.w*v.w;
#pragma unroll
            for (int off = 32; off > 0; off >>= 1) {
                sa += __shfl_down(sa, off);
                sb += __shfl_down(sb, off);
            }
            if (lane == 0) { red[0][wv] = sa; red[1][wv] = sb; }
            __syncthreads();
            if (tid == 0) {
                nrm[m]  = EPSF * (red[0][0] + red[0][1] + red[0][2] + red[0][3]);
                bdot[m] = red[1][0] + red[1][1] + red[1][2] + red[1][3];
            }
        }
        __syncthreads();
    }

    // ====== Phase 1b: LT = tril(L)^T -> bf16 fragment panels (via LDS) =====
    {
        const int k0 = (bid >> 4) * 64, n0 = (bid & 15) * 64;
        const int tn = tid & 63, tq = tid >> 6;
#pragma unroll
        for (int i = 0; i < 16; ++i) {
            int kk = tq + i * 4;
            int k = k0 + kk, n = n0 + tn;
            float v = (k >= n) ? L[k * D_DIM + n] : 0.f;  // coalesced in n
            s_tile[tn * 72 + kk] = f2bf(v);               // [n][k]
        }
        __syncthreads();
        const int p = tid >> 5, s = tid & 31;   // 8 panels x 32 threads
        const int np = p >> 1, kc2 = p & 1;
        const int ntile = (n0 >> 4) + np, kcg = (k0 >> 5) + kc2;
#pragma unroll
        for (int e = 0; e < 2; ++e) {
            int l = s * 2 + e;
            int lq = l >> 4, nr = l & 15;
            short8 vv = *(const short8*)&s_tile[(np * 16 + nr) * 72 + kc2 * 32 + lq * 8];
            *(short8*)(LT_frag + (ntile * 32 + kcg) * 512 + l * 8) = vv;
        }
        __syncthreads();
    }

    grid_barrier(bar, 1 * NBLK);

    // === Phase 2: P = A @ tril(L), one wave per 32x32 tile, 1152 jobs ======
    for (int j = gid; j < M_ALL * 32 / 32; j += 1024) {   // 1152 jobs
        const int mt = j >> 5, nt = j & 31;
        const unsigned short* Ab0 = A_frag  + ((2 * mt) * 32) * 512 + lane * 8;
        const unsigned short* Ab1 = Ab0 + 32 * 512;
        const unsigned short* Bb0 = LT_frag + ((2 * nt) * 32) * 512 + lane * 8;
        const unsigned short* Bb1 = Bb0 + 32 * 512;
        f32x4 acc[2][2] = {};
#pragma unroll 2
        for (int kc = nt; kc < 32; ++kc) {    // tri-skip: LT zero for k < n
            short8 a0 = *(const short8*)(Ab0 + kc * 512);
            short8 a1 = *(const short8*)(Ab1 + kc * 512);
            short8 b0 = *(const short8*)(Bb0 + kc * 512);
            short8 b1 = *(const short8*)(Bb1 + kc * 512);
            acc[0][0] = __builtin_amdgcn_mfma_f32_16x16x32_bf16(a0, b0, acc[0][0], 0, 0, 0);
            acc[0][1] = __builtin_amdgcn_mfma_f32_16x16x32_bf16(a0, b1, acc[0][1], 0, 0, 0);
            acc[1][0] = __builtin_amdgcn_mfma_f32_16x16x32_bf16(a1, b0, acc[1][0], 0, 0, 0);
            acc[1][1] = __builtin_amdgcn_mfma_f32_16x16x32_bf16(a1, b1, acc[1][1], 0, 0, 0);
        }
        // ||P_row||^2 partials: lane holds rows {mi*16+q*4+r}, cols {lrow, 16+lrow}
#pragma unroll
        for (int mi = 0; mi < 2; ++mi)
#pragma unroll
        for (int r = 0; r < 4; ++r) {
            float s = acc[mi][0][r] * acc[mi][0][r] + acc[mi][1][r] * acc[mi][1][r];
#pragma unroll
            for (int off = 1; off < 16; off <<= 1) s += __shfl_xor(s, off);
            if (lrow == 0) atomicAdd(&nrm[mt * 32 + mi * 16 + q * 4 + r], s);
        }
        // Reshuffle C-layout -> fragment layout through per-wave LDS (2KB)
        unsigned short* wls = s_tile + wv * 1024;
#pragma unroll
        for (int mi = 0; mi < 2; ++mi)
#pragma unroll
        for (int ni = 0; ni < 2; ++ni) {
            int lp = (ni * 2 + (lrow >> 3)) * 16 + q * 4;   // lane' base
#pragma unroll
            for (int r = 0; r < 4; ++r)
                wls[mi * 512 + (lp + r) * 8 + (lrow & 7)] = f2bf(acc[mi][ni][r]);
        }
        asm volatile("s_waitcnt lgkmcnt(0)" ::: "memory");
#pragma unroll
        for (int mi = 0; mi < 2; ++mi) {
            short8 vv = *(const short8*)(wls + mi * 512 + lane * 8);
            *(short8*)(P_frag + ((2 * mt + mi) * 32 + nt) * 512 + lane * 8) = vv;
        }
    }

    grid_barrier(bar, 2 * NBLK);

    // === Phase 3: fused cross-GEMM + epilogue, 504 wave-jobs ===============
    if (gid < 504) {
        const int bt = gid / 63, ct = gid % 63;
        const unsigned short* up = P_frag + (bt * 32) * 512 + lane * 8;        // u rows
        const unsigned short* vp = P_frag + ((8 + ct) * 32) * 512 + lane * 8;  // v rows
        f32x4 acc = {};
#pragma unroll 4
        for (int kc = 0; kc < 32; ++kc) {
            short8 a = *(const short8*)(up + kc * 512);
            short8 b = *(const short8*)(vp + kc * 512);
            acc = __builtin_amdgcn_mfma_f32_16x16x32_bf16(a, b, acc, 0, 0, 0);
        }
        const float lm = *lmbda_p, sc = *scale_p;
        const int c = ct * 16 + lrow;
        if (c < C_DIM) {
            float nm = nrm[B_DIM + c], bm = bdot[B_DIM + c];
#pragma unroll
            for (int r = 0; r < 4; ++r) {
                int b = bt * 16 + q * 4 + r;
                float quad = nrm[b] + nm - 2.f * acc[r] + EPSF;
                quad = fmaxf(quad, 0.f);
                float bd = bdot[b] - bm;
                out[b * C_DIM + c] = -sc * (sqrtf(quad) + lm * sqrtf(fmaf(bd, bd, EPSF)));
            }
        }
    }
}

extern "C" void kernel_launch(void* const* d_in, const int* in_sizes, int n_in,
                              void* d_out, int out_size, void* d_ws, size_t ws_size,
                              hipStream_t stream) {
    const float* x     = (const float*)d_in[0];   // [128,1024]
    const float* mu    = (const float*)d_in[1];   // [1000,1024]
    const float* beta  = (const float*)d_in[2];   // [1024]
    const float* L     = (const float*)d_in[3];   // [1024,1024]
    const float* lmbda = (const float*)d_in[4];
    const float* scale = (const float*)d_in[5];
    float* out = (float*)d_out;                   // [128,1000]

    char* ws = (char*)d_ws;
    unsigned short* A_frag  = (unsigned short*)ws;                       // 2359296 B
    unsigned short* LT_frag = (unsigned short*)(ws + 2359296);           // 2097152 B
    unsigned short* P_frag  = (unsigned short*)(ws + 2359296 + 2097152); // 2359296 B
    float* fws  = (float*)(ws + 2359296 + 2097152 + 2359296);
    float* nrm  = fws;             // [1152]
    float* bdot = fws + M_ALL;     // [1152]
    int*   bar  = (int*)(fws + 2 * M_ALL);

    hipMemsetAsync(bar, 0, sizeof(int), stream);   // capture-safe memset node
    fused<<<NBLK, 256, 0, stream>>>(x, mu, beta, L, lmbda, scale,
                                    A_frag, LT_frag, P_frag, nrm, bdot, bar, out);
}

// Round 5
// 98.793 us; speedup vs baseline: 1.9642x; 1.9642x over previous
//
#include <hip/hip_runtime.h>

#define D_DIM 1024
#define B_DIM 128
#define C_DIM 1000
#define M_ALL 1152   // 128 x-rows + 1000 mu-rows + 24 zero-pad rows
#define EPSF 1e-6f

typedef __attribute__((ext_vector_type(8))) short short8;   // 8 bf16 = 16B
typedef __attribute__((ext_vector_type(4))) float f32x4;

static __device__ __forceinline__ unsigned short f2bf(float f) {
    union { float f; unsigned int u; } v; v.f = f;
    unsigned int u = v.u;
    u += 0x7fffu + ((u >> 16) & 1u);   // round-to-nearest-even
    return (unsigned short)(u >> 16);
}

// Fragment layout (proven in R4): panel(tile16, kc) = 1KB. Element (row, k):
// kc = k>>5, l = ((k&31)>>3)*16 + row, j = k&7; offset = panel*512 + l*8 + j.
// One coalesced dwordx4/lane load per wave per panel = one MFMA A/B operand.

// ---------------------------------------------------------------------------
// Dispatch 1: blocks [0,1152): pack one A row -> fragment bf16 + per-row
// (eps*||a||^2, beta.a). Blocks [1152,1408): one 64x64 tril(L)^T tile -> frags.
// ---------------------------------------------------------------------------
__global__ __launch_bounds__(256)
void pack_all(const float* __restrict__ x, const float* __restrict__ mu,
              const float* __restrict__ beta, const float* __restrict__ L,
              unsigned short* __restrict__ A_frag, unsigned short* __restrict__ LT_frag,
              float* __restrict__ nrm, float* __restrict__ bdot) {
    __shared__ __align__(16) unsigned short s_tile[64 * 72];
    __shared__ float red[2][4];
    const int tid = threadIdx.x, bid = blockIdx.x;

    if (bid < M_ALL) {
        const int m = bid;
        float4 v;
        if (m < B_DIM)              v = *(const float4*)(x + m * D_DIM + tid * 4);
        else if (m < B_DIM + C_DIM) v = *(const float4*)(mu + (m - B_DIM) * D_DIM + tid * 4);
        else                        v = make_float4(0.f, 0.f, 0.f, 0.f);
        ushort4 o;
        o.x = f2bf(v.x); o.y = f2bf(v.y); o.z = f2bf(v.z); o.w = f2bf(v.w);
        // k = tid*4: kc = tid>>3, qk = (tid>>1)&3, j = (tid&1)*4
        int mtile = m >> 4, kc = tid >> 3, qk = (tid >> 1) & 3, jj = (tid & 1) * 4;
        *(ushort4*)(A_frag + (mtile * 32 + kc) * 512 + (qk * 16 + (m & 15)) * 8 + jj) = o;

        float4 bt4 = *(const float4*)(beta + tid * 4);
        float sa = v.x*v.x + v.y*v.y + v.z*v.z + v.w*v.w;
        float sb = bt4.x*v.x + bt4.y*v.y + bt4.z*v.z + bt4.w*v.w;
#pragma unroll
        for (int off = 32; off > 0; off >>= 1) {
            sa += __shfl_down(sa, off);
            sb += __shfl_down(sb, off);
        }
        int lane = tid & 63, wv = tid >> 6;
        if (lane == 0) { red[0][wv] = sa; red[1][wv] = sb; }
        __syncthreads();
        if (tid == 0) {
            nrm[m]  = EPSF * (red[0][0] + red[0][1] + red[0][2] + red[0][3]);
            bdot[m] = red[1][0] + red[1][1] + red[1][2] + red[1][3];
        }
    } else {
        const int t = bid - M_ALL;                 // 0..255
        const int k0 = (t >> 4) * 64, n0 = (t & 15) * 64;
        const int tn = tid & 63, tq = tid >> 6;    // tq in 0..3
#pragma unroll
        for (int i = 0; i < 16; ++i) {
            int kk = tq + i * 4;
            int k = k0 + kk, n = n0 + tn;
            float v = (k >= n) ? L[k * D_DIM + n] : 0.f;   // coalesced in n
            s_tile[tn * 72 + kk] = f2bf(v);                // [n][k]
        }
        __syncthreads();
        const int p = tid >> 5, s = tid & 31;      // 8 panels x 32 threads
        const int np = p >> 1, kc2 = p & 1;
        const int ntile = (n0 >> 4) + np, kcg = (k0 >> 5) + kc2;
#pragma unroll
        for (int e = 0; e < 2; ++e) {
            int l = s * 2 + e;
            int lq = l >> 4, nr = l & 15;
            short8 vv = *(const short8*)&s_tile[(np * 16 + nr) * 72 + kc2 * 32 + lq * 8];
            *(short8*)(LT_frag + (ntile * 32 + kcg) * 512 + l * 8) = vv;
        }
    }
}

// ---------------------------------------------------------------------------
// Dispatch 2: P = A @ tril(L). One wave per 32x32 tile, 1152 waves = 288 blk.
// Triangular K-skip; fragment-layout loads; unroll-4 for MLP. Epilogue:
// ||P_row||^2 atomics + C->fragment reshuffle through per-wave LDS.
// ---------------------------------------------------------------------------
__global__ __launch_bounds__(256)
void gemm_p(const unsigned short* __restrict__ A_frag,
            const unsigned short* __restrict__ LT_frag,
            unsigned short* __restrict__ P_frag, float* __restrict__ nrm) {
    __shared__ __align__(16) unsigned short s_resh[4 * 1024];   // 2KB per wave
    const int wv = threadIdx.x >> 6, lane = threadIdx.x & 63;
    const int wid = blockIdx.x * 4 + wv;           // 0..1151
    const int lrow = lane & 15, q = lane >> 4;
    const int mt = wid >> 5, nt = wid & 31;        // 4 waves/block share mt -> L1 reuse of A
    const unsigned short* Ab0 = A_frag  + ((2 * mt) * 32) * 512 + lane * 8;
    const unsigned short* Ab1 = Ab0 + 32 * 512;
    const unsigned short* Bb0 = LT_frag + ((2 * nt) * 32) * 512 + lane * 8;
    const unsigned short* Bb1 = Bb0 + 32 * 512;

    f32x4 acc[2][2] = {};
#pragma unroll 4
    for (int kc = nt; kc < 32; ++kc) {    // tri-skip: LT zero for k < n
        short8 a0 = *(const short8*)(Ab0 + kc * 512);
        short8 a1 = *(const short8*)(Ab1 + kc * 512);
        short8 b0 = *(const short8*)(Bb0 + kc * 512);
        short8 b1 = *(const short8*)(Bb1 + kc * 512);
        acc[0][0] = __builtin_amdgcn_mfma_f32_16x16x32_bf16(a0, b0, acc[0][0], 0, 0, 0);
        acc[0][1] = __builtin_amdgcn_mfma_f32_16x16x32_bf16(a0, b1, acc[0][1], 0, 0, 0);
        acc[1][0] = __builtin_amdgcn_mfma_f32_16x16x32_bf16(a1, b0, acc[1][0], 0, 0, 0);
        acc[1][1] = __builtin_amdgcn_mfma_f32_16x16x32_bf16(a1, b1, acc[1][1], 0, 0, 0);
    }

    // ||P_row||^2 partials (C layout: col = lrow + ni*16, row = q*4 + r)
#pragma unroll
    for (int mi = 0; mi < 2; ++mi)
#pragma unroll
    for (int r = 0; r < 4; ++r) {
        float s = acc[mi][0][r] * acc[mi][0][r] + acc[mi][1][r] * acc[mi][1][r];
#pragma unroll
        for (int off = 1; off < 16; off <<= 1) s += __shfl_xor(s, off);
        if (lrow == 0) atomicAdd(&nrm[mt * 32 + mi * 16 + q * 4 + r], s);
    }
    // Reshuffle C-layout -> fragment layout through per-wave LDS
    unsigned short* wls = s_resh + wv * 1024;
#pragma unroll
    for (int mi = 0; mi < 2; ++mi)
#pragma unroll
    for (int ni = 0; ni < 2; ++ni) {
        int lp = (ni * 2 + (lrow >> 3)) * 16 + q * 4;
#pragma unroll
        for (int r = 0; r < 4; ++r)
            wls[mi * 512 + (lp + r) * 8 + (lrow & 7)] = f2bf(acc[mi][ni][r]);
    }
    asm volatile("s_waitcnt lgkmcnt(0)" ::: "memory");   // per-wave: no barrier needed
#pragma unroll
    for (int mi = 0; mi < 2; ++mi) {
        short8 vv = *(const short8*)(wls + mi * 512 + lane * 8);
        *(short8*)(P_frag + ((2 * mt + mi) * 32 + nt) * 512 + lane * 8) = vv;
    }
}

// ---------------------------------------------------------------------------
// Dispatch 3: cross-GEMM + fused epilogue. One wave per 16x16 out tile,
// 504 waves = 126 blocks, fragment loads, unroll-8 for MLP.
// ---------------------------------------------------------------------------
__global__ __launch_bounds__(256)
void gemm_cross(const unsigned short* __restrict__ P_frag,
                const float* __restrict__ nrm, const float* __restrict__ bdot,
                const float* __restrict__ lmbda_p, const float* __restrict__ scale_p,
                float* __restrict__ out) {
    const int wid  = blockIdx.x * 4 + (threadIdx.x >> 6);   // 0..503
    const int lane = threadIdx.x & 63;
    const int lrow = lane & 15, q = lane >> 4;
    const int bt = wid / 63, ct = wid % 63;
    const unsigned short* up = P_frag + (bt * 32) * 512 + lane * 8;        // u rows
    const unsigned short* vp = P_frag + ((8 + ct) * 32) * 512 + lane * 8;  // v rows

    f32x4 acc = {};
#pragma unroll 8
    for (int kc = 0; kc < 32; ++kc) {
        short8 a = *(const short8*)(up + kc * 512);
        short8 b = *(const short8*)(vp + kc * 512);
        acc = __builtin_amdgcn_mfma_f32_16x16x32_bf16(a, b, acc, 0, 0, 0);
    }
    const float lm = *lmbda_p, sc = *scale_p;
    const int c = ct * 16 + lrow;
    if (c < C_DIM) {
        float nm = nrm[B_DIM + c], bm = bdot[B_DIM + c];
#pragma unroll
        for (int r = 0; r < 4; ++r) {
            int b = bt * 16 + q * 4 + r;
            float quad = nrm[b] + nm - 2.f * acc[r] + EPSF;
            quad = fmaxf(quad, 0.f);
            float bd = bdot[b] - bm;
            out[b * C_DIM + c] = -sc * (sqrtf(quad) + lm * sqrtf(fmaf(bd, bd, EPSF)));
        }
    }
}

extern "C" void kernel_launch(void* const* d_in, const int* in_sizes, int n_in,
                              void* d_out, int out_size, void* d_ws, size_t ws_size,
                              hipStream_t stream) {
    const float* x     = (const float*)d_in[0];   // [128,1024]
    const float* mu    = (const float*)d_in[1];   // [1000,1024]
    const float* beta  = (const float*)d_in[2];   // [1024]
    const float* L     = (const float*)d_in[3];   // [1024,1024]
    const float* lmbda = (const float*)d_in[4];
    const float* scale = (const float*)d_in[5];
    float* out = (float*)d_out;                   // [128,1000]

    char* ws = (char*)d_ws;
    unsigned short* A_frag  = (unsigned short*)ws;                       // 2359296 B
    unsigned short* LT_frag = (unsigned short*)(ws + 2359296);           // 2097152 B
    unsigned short* P_frag  = (unsigned short*)(ws + 2359296 + 2097152); // 2359296 B
    float* fws  = (float*)(ws + 2359296 + 2097152 + 2359296);
    float* nrm  = fws;             // [1152]
    float* bdot = fws + M_ALL;     // [1152]

    dim3 blk(256);
    pack_all  <<<M_ALL + 256, blk, 0, stream>>>(x, mu, beta, L, A_frag, LT_frag, nrm, bdot);
    gemm_p    <<<288, blk, 0, stream>>>(A_frag, LT_frag, P_frag, nrm);
    gemm_cross<<<126, blk, 0, stream>>>(P_frag, nrm, bdot, lmbda, scale, out);
}